// Round 2
// baseline (765.807 us; speedup 1.0000x reference)
//
#include <hip/hip_runtime.h>

#define NROWS  250000
#define DIM    512
#define TOPK   11        // 1 + K from reference top_k
#define KNEIGH 9         // idx[1:K] with K=10 -> 9 neighbors (reference slice)
#define NCLS   100
#define NB     2048      // stage-1 blocks
#define TPB    256
#define WPB    4         // waves per block
#define NWAVES (NB * WPB)                        // 8192
#define RPW    32                                // rows per wave (8192*32 = 262144 >= 250000)
#define RB     4                                 // rows per batch iteration (ILP)
#define NC     (NB * TOPK)                       // stage-2 candidates = 22528

typedef float v4f __attribute__((ext_vector_type(4)));

__device__ __forceinline__ bool better(float v1, int i1, float v2, int i2) {
    // lax.top_k order: value descending, index ascending on ties
    return (v1 > v2) || ((v1 == v2) && (i1 < i2));
}

__global__ __launch_bounds__(TPB) void knn_stage1(
    const float* __restrict__ emb,
    const float* __restrict__ coll,
    float* __restrict__ cand_v,
    int*   __restrict__ cand_i)
{
    const int lane = threadIdx.x & 63;
    const int warp = threadIdx.x >> 6;
    const int wid  = blockIdx.x * WPB + warp;

    // embedding fragment: lane covers e[lane*8 .. lane*8+8)
    const v4f e0 = *(const v4f*)(emb + lane * 8);
    const v4f e1 = *(const v4f*)(emb + lane * 8 + 4);
    float es = e0.x*e0.x + e0.y*e0.y + e0.z*e0.z + e0.w*e0.w
             + e1.x*e1.x + e1.y*e1.y + e1.z*e1.z + e1.w*e1.w;
    #pragma unroll
    for (int s = 1; s < 64; s <<= 1) es += __shfl_xor(es, s, 64);
    const float edenom = sqrtf(es + 1e-12f);

    float tv[TOPK];
    int   ti[TOPK];
    #pragma unroll
    for (int j = 0; j < TOPK; ++j) { tv[j] = -__builtin_inff(); ti[j] = 0x7fffffff; }

    const int row0 = wid * RPW;
    for (int rb = 0; rb < RPW; rb += RB) {
        const int rbase = row0 + rb;
        if (rbase >= NROWS) break;

        // --- issue all 8 loads up front (4 rows x 2 float4): MLP ---
        v4f a0[RB], a1[RB];
        #pragma unroll
        for (int k = 0; k < RB; ++k) {
            const int row = min(rbase + k, NROWS - 1);   // clamp addr; guard insert later
            const float* p = coll + (size_t)row * DIM + lane * 8;
            a0[k] = __builtin_nontemporal_load((const v4f*)p);
            a1[k] = __builtin_nontemporal_load((const v4f*)(p + 4));
        }

        // --- per-lane partial dot & norm for 4 rows ---
        float dot[RB], nrm[RB];
        #pragma unroll
        for (int k = 0; k < RB; ++k) {
            dot[k] = a0[k].x*e0.x + a0[k].y*e0.y + a0[k].z*e0.z + a0[k].w*e0.w
                   + a1[k].x*e1.x + a1[k].y*e1.y + a1[k].z*e1.z + a1[k].w*e1.w;
            nrm[k] = a0[k].x*a0[k].x + a0[k].y*a0[k].y + a0[k].z*a0[k].z + a0[k].w*a0[k].w
                   + a1[k].x*a1[k].x + a1[k].y*a1[k].y + a1[k].z*a1[k].z + a1[k].w*a1[k].w;
        }

        // --- butterfly reduce 8 independent values: 6 rounds, ILP=8 ---
        #pragma unroll
        for (int s = 1; s < 64; s <<= 1) {
            #pragma unroll
            for (int k = 0; k < RB; ++k) {
                dot[k] += __shfl_xor(dot[k], s, 64);
                nrm[k] += __shfl_xor(nrm[k], s, 64);
            }
        }

        // --- wave-uniform replicated top-11 insert, 4 rows ---
        #pragma unroll
        for (int k = 0; k < RB; ++k) {
            const int row = rbase + k;
            if (row >= NROWS) break;
            const float sim = dot[k] / (sqrtf(nrm[k] + 1e-12f) * edenom);
            if (better(sim, row, tv[TOPK-1], ti[TOPK-1])) {
                tv[TOPK-1] = sim; ti[TOPK-1] = row;
                #pragma unroll
                for (int j = TOPK-1; j > 0; --j) {
                    if (better(tv[j], ti[j], tv[j-1], ti[j-1])) {
                        float fv = tv[j]; tv[j] = tv[j-1]; tv[j-1] = fv;
                        int   fi = ti[j]; ti[j] = ti[j-1]; ti[j-1] = fi;
                    } else break;
                }
            }
        }
    }

    // merge 4 wave-local top-11 lists -> block top-11
    __shared__ float sv[WPB * TOPK];
    __shared__ int   si[WPB * TOPK];
    if (lane == 0) {
        #pragma unroll
        for (int j = 0; j < TOPK; ++j) { sv[warp*TOPK + j] = tv[j]; si[warp*TOPK + j] = ti[j]; }
    }
    __syncthreads();
    if (warp == 0) {
        float v = (lane < WPB*TOPK) ? sv[lane] : -__builtin_inff();
        int   i = (lane < WPB*TOPK) ? si[lane] : 0x7fffffff;
        for (int r = 0; r < TOPK; ++r) {
            float bv = v; int bi = i;
            #pragma unroll
            for (int s = 1; s < 64; s <<= 1) {
                float ov = __shfl_xor(bv, s, 64);
                int   oi = __shfl_xor(bi, s, 64);
                if (better(ov, oi, bv, bi)) { bv = ov; bi = oi; }
            }
            if (v == bv && i == bi) v = -__builtin_inff();  // row indices unique -> one holder
            if (lane == 0) { cand_v[blockIdx.x*TOPK + r] = bv; cand_i[blockIdx.x*TOPK + r] = bi; }
        }
    }
}

__global__ __launch_bounds__(TPB) void knn_stage2(
    const float* __restrict__ cand_v,
    const int*   __restrict__ cand_i,
    const int*   __restrict__ labels,
    float* __restrict__ out)
{
    const int tid  = threadIdx.x;
    const int lane = tid & 63;
    const int warp = tid >> 6;

    // per-thread sorted top-11 over strided candidate subset (+1 pad slot for head ptr)
    float tv[TOPK + 1];
    int   ti[TOPK + 1];
    #pragma unroll
    for (int j = 0; j < TOPK + 1; ++j) { tv[j] = -__builtin_inff(); ti[j] = 0x7fffffff; }

    for (int j = tid; j < NC; j += TPB) {
        float v = cand_v[j]; int i = cand_i[j];
        if (better(v, i, tv[TOPK-1], ti[TOPK-1])) {
            tv[TOPK-1] = v; ti[TOPK-1] = i;
            #pragma unroll
            for (int q = TOPK-1; q > 0; --q) {
                if (better(tv[q], ti[q], tv[q-1], ti[q-1])) {
                    float fv = tv[q]; tv[q] = tv[q-1]; tv[q-1] = fv;
                    int   fi = ti[q]; ti[q] = ti[q-1]; ti[q-1] = fi;
                } else break;
            }
        }
    }

    __shared__ float lv[TPB * (TOPK + 1)];
    __shared__ int   li[TPB * (TOPK + 1)];
    #pragma unroll
    for (int j = 0; j < TOPK + 1; ++j) {
        lv[tid*(TOPK+1) + j] = tv[j];
        li[tid*(TOPK+1) + j] = ti[j];
    }

    __shared__ float rv[TOPK];
    __shared__ int   ri[TOPK];
    __shared__ float wv_[TPB/64];
    __shared__ int   wi_[TPB/64], wt_[TPB/64];
    __shared__ int   winner;
    __syncthreads();

    // k-way merge: each thread's list is sorted; 11 rounds of argmax over heads
    int p = 0;
    for (int r = 0; r < TOPK; ++r) {
        float cv = lv[tid*(TOPK+1) + p];
        int   ci = li[tid*(TOPK+1) + p];
        int   ct = tid;
        #pragma unroll
        for (int s = 1; s < 64; s <<= 1) {
            float ov = __shfl_xor(cv, s, 64);
            int   oi = __shfl_xor(ci, s, 64);
            int   ot = __shfl_xor(ct, s, 64);
            if (better(ov, oi, cv, ci)) { cv = ov; ci = oi; ct = ot; }
        }
        if (lane == 0) { wv_[warp] = cv; wi_[warp] = ci; wt_[warp] = ct; }
        __syncthreads();
        if (tid == 0) {
            float bv = wv_[0]; int bi = wi_[0]; int bt = wt_[0];
            for (int w = 1; w < TPB/64; ++w)
                if (better(wv_[w], wi_[w], bv, bi)) { bv = wv_[w]; bi = wi_[w]; bt = wt_[w]; }
            rv[r] = bv; ri[r] = bi; winner = bt;
        }
        __syncthreads();
        if (tid == winner) ++p;   // winner advances its sorted-list head
    }
    __syncthreads();

    if (tid == 0) {
        #pragma unroll
        for (int j = 0; j < TOPK; ++j) out[j] = rv[j];

        // vote over labels of idx[1:10] (9 neighbors, faithful to reference slice)
        int cnt[NCLS];
        for (int c = 0; c < NCLS; ++c) cnt[c] = 0;
        int preds[KNEIGH];
        for (int j = 0; j < KNEIGH; ++j) {
            preds[j] = labels[ri[1 + j]];
            ++cnt[preds[j]];
        }
        int best = 0, bc = cnt[0];
        for (int c = 1; c < NCLS; ++c) if (cnt[c] > bc) { bc = cnt[c]; best = c; }  // first max
        int cp = 0;
        for (int j = KNEIGH - 1; j >= 0; --j) if (preds[j] == best) cp = j;          // first match
        out[11] = (float)best;       // pred_int
        out[12] = rv[1 + cp];        // confidence = probs[conf_pos] = vals[1+conf_pos]
    }
}

extern "C" void kernel_launch(void* const* d_in, const int* in_sizes, int n_in,
                              void* d_out, int out_size, void* d_ws, size_t ws_size,
                              hipStream_t stream) {
    const float* emb    = (const float*)d_in[0];
    const float* coll   = (const float*)d_in[1];
    const int*   labels = (const int*)d_in[2];
    float*       out    = (float*)d_out;

    float* cand_v = (float*)d_ws;            // NC floats
    int*   cand_i = (int*)(cand_v + NC);     // NC ints  (total ~180 KB of ws)

    knn_stage1<<<NB, TPB, 0, stream>>>(emb, coll, cand_v, cand_i);
    knn_stage2<<<1, TPB, 0, stream>>>(cand_v, cand_i, labels, out);
}

// Round 3
// 686.539 us; speedup vs baseline: 1.1155x; 1.1155x over previous
//
#include <hip/hip_runtime.h>

#define NROWS  250000
#define DIM    512
#define TOPK   11        // 1 + K from reference top_k
#define KNEIGH 9         // idx[1:K] with K=10 -> 9 neighbors (reference slice)
#define NCLS   100
#define NB     1024      // stage-1 blocks
#define TPB    256
#define WPB    4         // waves per block
#define NWAVES (NB * WPB)                        // 4096
#define NGROUPS (NROWS / 4)                      // 62500 groups of 4 rows (exact)
#define NC     (NB * TOPK)                       // stage-2 candidates = 11264

typedef float v4f __attribute__((ext_vector_type(4)));

__device__ __forceinline__ bool better(float v1, int i1, float v2, int i2) {
    // lax.top_k order: value descending, index ascending on ties
    return (v1 > v2) || ((v1 == v2) && (i1 < i2));
}

__global__ __launch_bounds__(TPB) void knn_stage1(
    const float* __restrict__ emb,
    const float* __restrict__ coll,
    float* __restrict__ cand_v,
    int*   __restrict__ cand_i)
{
    const int lane = threadIdx.x & 63;
    const int warp = threadIdx.x >> 6;
    const int wid  = blockIdx.x * WPB + warp;
    const int q    = lane >> 4;      // quarter 0..3 -> row within group
    const int j    = lane & 15;      // lane within quarter

    // embedding fragment: lane j covers float4s {c*16+j : c=0..7} (32 floats)
    const float* ep = emb + 4 * j;
    v4f e[8];
    #pragma unroll
    for (int c = 0; c < 8; ++c) e[c] = *(const v4f*)(ep + 64 * c);
    float es = 0.f;
    #pragma unroll
    for (int c = 0; c < 8; ++c)
        es += e[c].x*e[c].x + e[c].y*e[c].y + e[c].z*e[c].z + e[c].w*e[c].w;
    #pragma unroll
    for (int s = 1; s < 16; s <<= 1) es += __shfl_xor(es, s, 64);  // quarter allreduce
    const float edenom = sqrtf(es + 1e-12f);

    float tv[TOPK];
    int   ti[TOPK];
    #pragma unroll
    for (int t = 0; t < TOPK; ++t) { tv[t] = -__builtin_inff(); ti[t] = 0x7fffffff; }

    const float* base = coll + 4 * j;
    for (int g = wid; g < NGROUPS; g += NWAVES) {
        const int row = 4 * g + q;                 // quarter q handles row 4g+q
        const float* p = base + (size_t)row * DIM;

        v4f a[8];
        #pragma unroll
        for (int c = 0; c < 8; ++c)
            a[c] = __builtin_nontemporal_load((const v4f*)(p + 64 * c));

        float dot = 0.f, nrm = 0.f;
        #pragma unroll
        for (int c = 0; c < 8; ++c) {
            dot += a[c].x*e[c].x + a[c].y*e[c].y + a[c].z*e[c].z + a[c].w*e[c].w;
            nrm += a[c].x*a[c].x + a[c].y*a[c].y + a[c].z*a[c].z + a[c].w*a[c].w;
        }
        // 4 rows reduced simultaneously: butterfly within each 16-lane quarter
        #pragma unroll
        for (int s = 1; s < 16; s <<= 1) {
            dot += __shfl_xor(dot, s, 64);
            nrm += __shfl_xor(nrm, s, 64);
        }
        const float simq = dot / (sqrtf(nrm + 1e-12f) * edenom);

        // broadcast each quarter's sim -> wave-uniform top-11 insert (x4 rows)
        #pragma unroll
        for (int qq = 0; qq < 4; ++qq) {
            const float sim = __shfl(simq, qq * 16, 64);
            const int   row_q = 4 * g + qq;
            if (better(sim, row_q, tv[TOPK-1], ti[TOPK-1])) {
                tv[TOPK-1] = sim; ti[TOPK-1] = row_q;
                #pragma unroll
                for (int t = TOPK-1; t > 0; --t) {
                    if (better(tv[t], ti[t], tv[t-1], ti[t-1])) {
                        float fv = tv[t]; tv[t] = tv[t-1]; tv[t-1] = fv;
                        int   fi = ti[t]; ti[t] = ti[t-1]; ti[t-1] = fi;
                    } else break;
                }
            }
        }
    }

    // merge 4 wave-local top-11 lists -> block top-11
    __shared__ float sv[WPB * TOPK];
    __shared__ int   si[WPB * TOPK];
    if (lane == 0) {
        #pragma unroll
        for (int t = 0; t < TOPK; ++t) { sv[warp*TOPK + t] = tv[t]; si[warp*TOPK + t] = ti[t]; }
    }
    __syncthreads();
    if (warp == 0) {
        float v = (lane < WPB*TOPK) ? sv[lane] : -__builtin_inff();
        int   i = (lane < WPB*TOPK) ? si[lane] : 0x7fffffff;
        for (int r = 0; r < TOPK; ++r) {
            float bv = v; int bi = i;
            #pragma unroll
            for (int s = 1; s < 64; s <<= 1) {
                float ov = __shfl_xor(bv, s, 64);
                int   oi = __shfl_xor(bi, s, 64);
                if (better(ov, oi, bv, bi)) { bv = ov; bi = oi; }
            }
            if (v == bv && i == bi) v = -__builtin_inff();  // row indices unique -> one holder
            if (lane == 0) { cand_v[blockIdx.x*TOPK + r] = bv; cand_i[blockIdx.x*TOPK + r] = bi; }
        }
    }
}

__global__ __launch_bounds__(TPB) void knn_stage2(
    const float* __restrict__ cand_v,
    const int*   __restrict__ cand_i,
    const int*   __restrict__ labels,
    float* __restrict__ out)
{
    const int tid  = threadIdx.x;
    const int lane = tid & 63;
    const int warp = tid >> 6;

    // per-thread sorted top-11 over strided candidate subset (+1 pad slot for head ptr)
    float tv[TOPK + 1];
    int   ti[TOPK + 1];
    #pragma unroll
    for (int t = 0; t < TOPK + 1; ++t) { tv[t] = -__builtin_inff(); ti[t] = 0x7fffffff; }

    for (int c = tid; c < NC; c += TPB) {
        float v = cand_v[c]; int i = cand_i[c];
        if (better(v, i, tv[TOPK-1], ti[TOPK-1])) {
            tv[TOPK-1] = v; ti[TOPK-1] = i;
            #pragma unroll
            for (int t = TOPK-1; t > 0; --t) {
                if (better(tv[t], ti[t], tv[t-1], ti[t-1])) {
                    float fv = tv[t]; tv[t] = tv[t-1]; tv[t-1] = fv;
                    int   fi = ti[t]; ti[t] = ti[t-1]; ti[t-1] = fi;
                } else break;
            }
        }
    }

    __shared__ float lv[TPB * (TOPK + 1)];
    __shared__ int   li[TPB * (TOPK + 1)];
    #pragma unroll
    for (int t = 0; t < TOPK + 1; ++t) {
        lv[tid*(TOPK+1) + t] = tv[t];
        li[tid*(TOPK+1) + t] = ti[t];
    }

    __shared__ float rv[TOPK];
    __shared__ int   ri[TOPK];
    __shared__ float wv_[TPB/64];
    __shared__ int   wi_[TPB/64], wt_[TPB/64];
    __shared__ int   winner;
    __syncthreads();

    // k-way merge: each thread's list is sorted; 11 rounds of argmax over heads
    int p = 0;
    for (int r = 0; r < TOPK; ++r) {
        float cv = lv[tid*(TOPK+1) + p];
        int   ci = li[tid*(TOPK+1) + p];
        int   ct = tid;
        #pragma unroll
        for (int s = 1; s < 64; s <<= 1) {
            float ov = __shfl_xor(cv, s, 64);
            int   oi = __shfl_xor(ci, s, 64);
            int   ot = __shfl_xor(ct, s, 64);
            if (better(ov, oi, cv, ci)) { cv = ov; ci = oi; ct = ot; }
        }
        if (lane == 0) { wv_[warp] = cv; wi_[warp] = ci; wt_[warp] = ct; }
        __syncthreads();
        if (tid == 0) {
            float bv = wv_[0]; int bi = wi_[0]; int bt = wt_[0];
            for (int w = 1; w < TPB/64; ++w)
                if (better(wv_[w], wi_[w], bv, bi)) { bv = wv_[w]; bi = wi_[w]; bt = wt_[w]; }
            rv[r] = bv; ri[r] = bi; winner = bt;
        }
        __syncthreads();
        if (tid == winner) ++p;   // winner advances its sorted-list head
    }
    __syncthreads();

    if (tid == 0) {
        #pragma unroll
        for (int t = 0; t < TOPK; ++t) out[t] = rv[t];

        // vote over labels of idx[1:10] (9 neighbors, faithful to reference slice)
        int cnt[NCLS];
        for (int c = 0; c < NCLS; ++c) cnt[c] = 0;
        int preds[KNEIGH];
        for (int t = 0; t < KNEIGH; ++t) {
            preds[t] = labels[ri[1 + t]];
            ++cnt[preds[t]];
        }
        int best = 0, bc = cnt[0];
        for (int c = 1; c < NCLS; ++c) if (cnt[c] > bc) { bc = cnt[c]; best = c; }  // first max
        int cp = 0;
        for (int t = KNEIGH - 1; t >= 0; --t) if (preds[t] == best) cp = t;          // first match
        out[11] = (float)best;       // pred_int
        out[12] = rv[1 + cp];        // confidence = probs[conf_pos] = vals[1+conf_pos]
    }
}

extern "C" void kernel_launch(void* const* d_in, const int* in_sizes, int n_in,
                              void* d_out, int out_size, void* d_ws, size_t ws_size,
                              hipStream_t stream) {
    const float* emb    = (const float*)d_in[0];
    const float* coll   = (const float*)d_in[1];
    const int*   labels = (const int*)d_in[2];
    float*       out    = (float*)d_out;

    float* cand_v = (float*)d_ws;            // NC floats
    int*   cand_i = (int*)(cand_v + NC);     // NC ints  (total ~90 KB of ws)

    knn_stage1<<<NB, TPB, 0, stream>>>(emb, coll, cand_v, cand_i);
    knn_stage2<<<1, TPB, 0, stream>>>(cand_v, cand_i, labels, out);
}